// Round 6
// baseline (411.071 us; speedup 1.0000x reference)
//
#include <hip/hip_runtime.h>
#include <hip/hip_bf16.h>

typedef __attribute__((ext_vector_type(4))) float f32x4;
typedef __attribute__((ext_vector_type(8))) short short8;
typedef unsigned short u16;
typedef unsigned long long u64;

static __device__ __forceinline__ u16 f2bf(float f) {
    __hip_bfloat16 h = __float2bfloat16(f);
    return __builtin_bit_cast(u16, h);
}
static __device__ __forceinline__ float bf2f(u16 u) {
    unsigned int w = ((unsigned int)u) << 16;
    return __builtin_bit_cast(float, w);
}

// ---------------- x (f32) -> x_bf (bf16) streaming convert ----------------
__global__ void k_cvt(const float* __restrict__ x, u16* __restrict__ xb, int total8) {
    const float4* x4 = (const float4*)x;
    int stride = gridDim.x * blockDim.x;
    for (int i = blockIdx.x * blockDim.x + threadIdx.x; i < total8; i += stride) {
        float4 a = x4[i * 2], b = x4[i * 2 + 1];
        union { u16 u[8]; short8 v; } o;
        o.u[0] = f2bf(a.x); o.u[1] = f2bf(a.y); o.u[2] = f2bf(a.z); o.u[3] = f2bf(a.w);
        o.u[4] = f2bf(b.x); o.u[5] = f2bf(b.y); o.u[6] = f2bf(b.z); o.u[7] = f2bf(b.w);
        *(short8*)(xb + (size_t)i * 8) = o.v;
    }
}

// ---------------- bucket edges by dst range; LDS-staged 2KB-chunk flush ----------
// Every 1KB global chunk is written contiguously by ONE block -> full-line writes,
// no cross-XCD partial-line eviction.
__global__ __launch_bounds__(256) void k_bucket(
    const int* __restrict__ src, const int* __restrict__ dst,
    int* __restrict__ bcnt, int* __restrict__ bsrc, int* __restrict__ bdst,
    int cap, int E, int chunk) {
    __shared__ int sbuf[8][512];
    __shared__ int dbuf[8][512];
    __shared__ int cnt[8];
    int tid = threadIdx.x, lane = tid & 63, wv = tid >> 6;
    if (tid < 8) cnt[tid] = 0;
    __syncthreads();
    int stride = gridDim.x * 256;
    for (int eb = blockIdx.x * 256; eb < E; eb += stride) {
        int e = eb + tid;
        bool val = e < E;
        int s = 0, d = 0, b = -1;
        if (val) { s = src[e]; d = dst[e]; b = d / chunk; }
#pragma unroll
        for (int bb = 0; bb < 8; ++bb) {
            u64 m = __ballot(val && (b == bb));
            if (m == 0) continue;
            int total = (int)__popcll(m);
            int leader = __ffsll((unsigned long long)m) - 1;
            int lbase = 0;
            if (lane == leader) lbase = atomicAdd(&cnt[bb], total);
            lbase = __shfl(lbase, leader, 64);
            if (val && b == bb) {
                int rank = (int)__popcll(m & ((1ull << lane) - 1ull));
                sbuf[bb][lbase + rank] = s;
                dbuf[bb][lbase + rank] = d;
            }
        }
        __syncthreads();
        // flush full 256-chunks: wave wv owns buckets 2wv, 2wv+1
#pragma unroll
        for (int t = 0; t < 2; ++t) {
            int bb = wv * 2 + t;
            int c0 = cnt[bb];
            if (c0 >= 256) {
                int g;
                if (lane == 0) g = atomicAdd(&bcnt[bb], 256);
                g = __shfl(g, 0, 64);
                size_t base = (size_t)bb * cap + g;
#pragma unroll
                for (int i = 0; i < 4; ++i) {
                    int idx = i * 64 + lane;
                    bsrc[base + idx] = sbuf[bb][idx];
                    bdst[base + idx] = dbuf[bb][idx];
                }
                int rem = c0 - 256;
                for (int i = lane; i < rem; i += 64) {
                    sbuf[bb][i] = sbuf[bb][256 + i];
                    dbuf[bb][i] = dbuf[bb][256 + i];
                }
                if (lane == 0) cnt[bb] = rem;
            }
        }
        __syncthreads();
    }
    // drain partial chunks (contiguous runs; boundary lines only are partial)
#pragma unroll
    for (int t = 0; t < 2; ++t) {
        int bb = wv * 2 + t;
        int c0 = cnt[bb];
        if (c0 > 0) {
            int g;
            if (lane == 0) g = atomicAdd(&bcnt[bb], c0);
            g = __shfl(g, 0, 64);
            size_t base = (size_t)bb * cap + g;
            for (int i = lane; i < c0; i += 64) {
                bsrc[base + i] = sbuf[bb][i];
                bdst[base + i] = dbuf[bb][i];
            }
        }
    }
}

// ---------------- degree count from buckets, XCD-pinned (L2-local atomics) -------
__global__ void k_deg2(const int* __restrict__ bdst, const int* __restrict__ bcnt,
                       int* __restrict__ deg, int cap) {
    int b = blockIdx.x & 7;
    int nb = gridDim.x >> 3;
    int bs = blockIdx.x >> 3;
    int cnt = bcnt[b];
    const int* bp = bdst + (size_t)b * cap;
    for (int i = bs * 256 + threadIdx.x; i < cnt; i += nb * 256)
        atomicAdd(&deg[bp[i]], 1);
}

// ---------------- 3-kernel exclusive scan over deg[N] ----------------
__global__ void k_scan_a(const int* __restrict__ deg, int* __restrict__ bsum, int n) {
    __shared__ int s[256];
    int tid = threadIdx.x;
    int i = blockIdx.x * 256 + tid;
    s[tid] = (i < n) ? deg[i] : 0;
    __syncthreads();
    for (int ofs = 128; ofs > 0; ofs >>= 1) {
        if (tid < ofs) s[tid] += s[tid + ofs];
        __syncthreads();
    }
    if (tid == 0) bsum[blockIdx.x] = s[0];
}

__global__ void k_scan_b(const int* __restrict__ bsum, int* __restrict__ boff, int nb,
                         int* __restrict__ offN) {
    __shared__ int s[512];
    int tid = threadIdx.x;
    int v = (tid < nb) ? bsum[tid] : 0;
    s[tid] = v;
    __syncthreads();
    for (int ofs = 1; ofs < 512; ofs <<= 1) {
        int t = (tid >= ofs) ? s[tid - ofs] : 0;
        __syncthreads();
        s[tid] += t;
        __syncthreads();
    }
    if (tid < nb) boff[tid] = s[tid] - v;          // exclusive
    if (tid == nb - 1) offN[0] = s[tid];           // total = E
}

__global__ void k_scan_c(const int* __restrict__ deg, const int* __restrict__ boff,
                         int* __restrict__ off, int* __restrict__ cur, int n) {
    __shared__ int s[256];
    int tid = threadIdx.x;
    int i = blockIdx.x * 256 + tid;
    int v = (i < n) ? deg[i] : 0;
    s[tid] = v;
    __syncthreads();
    for (int ofs = 1; ofs < 256; ofs <<= 1) {
        int t = (tid >= ofs) ? s[tid - ofs] : 0;
        __syncthreads();
        s[tid] += t;
        __syncthreads();
    }
    int excl = s[tid] - v + boff[blockIdx.x];
    if (i < n) { off[i] = excl; cur[i] = excl; }
}

// ---------------- CSR place from buckets, XCD-pinned ----------------
__global__ void k_fill2(const int* __restrict__ bsrc, const int* __restrict__ bdst,
                        const int* __restrict__ bcnt, int* __restrict__ cur,
                        int* __restrict__ csr, int cap) {
    int b = blockIdx.x & 7;
    int nb = gridDim.x >> 3;
    int bs = blockIdx.x >> 3;
    int cnt = bcnt[b];
    size_t base = (size_t)b * cap;
    for (int i = bs * 256 + threadIdx.x; i < cnt; i += nb * 256) {
        int d = bdst[base + i];
        int p = atomicAdd(&cur[d], 1);
        csr[p] = bsrc[base + i];
    }
}

// ------ pull-aggregate: one wave per node, 4 edge slots x 16 lanes x 16B --------
__global__ void k_aggr(const u16* __restrict__ xb, const int* __restrict__ off,
                       const int* __restrict__ csr, u16* __restrict__ aggr, int n) {
    int node = (blockIdx.x * blockDim.x + threadIdx.x) >> 6;
    if (node >= n) return;
    int lane = threadIdx.x & 63;
    int c = lane & 15;    // 16B slot (8 bf16), 16 slots = 256B row
    int j = lane >> 4;    // edge slot 0..3
    const short8* x8 = (const short8*)xb;
    int s0 = off[node], s1 = off[node + 1];
    float acc[8] = {0.f, 0.f, 0.f, 0.f, 0.f, 0.f, 0.f, 0.f};
    int e = s0;
    for (; e + 8 <= s1; e += 8) {   // 2 rows per slot in flight
        short8 va = x8[(size_t)csr[e + j] * 16 + c];
        short8 vb = x8[(size_t)csr[e + j + 4] * 16 + c];
#pragma unroll
        for (int i = 0; i < 8; ++i)
            acc[i] += bf2f((u16)va[i]) + bf2f((u16)vb[i]);
    }
    {   // tail: up to 7 edges, per-slot guards
        int r1 = e + j, r2 = e + j + 4;
        if (r1 < s1) {
            short8 va = x8[(size_t)csr[r1] * 16 + c];
#pragma unroll
            for (int i = 0; i < 8; ++i) acc[i] += bf2f((u16)va[i]);
        }
        if (r2 < s1) {
            short8 vb = x8[(size_t)csr[r2] * 16 + c];
#pragma unroll
            for (int i = 0; i < 8; ++i) acc[i] += bf2f((u16)vb[i]);
        }
    }
#pragma unroll
    for (int i = 0; i < 8; ++i) {
        acc[i] += __shfl_xor(acc[i], 16, 64);
        acc[i] += __shfl_xor(acc[i], 32, 64);
    }
    if (j == 0) {
        short8 sv = x8[(size_t)node * 16 + c];   // self loop
        float inv = 1.0f / (float)(s1 - s0 + 1);
        short8 o;
#pragma unroll
        for (int i = 0; i < 8; ++i)
            o[i] = (short)f2bf((acc[i] + bf2f((u16)sv[i])) * inv);
        *(short8*)(aggr + (size_t)node * 128 + c * 8) = o;
    }
}

// ------- pass1: linear(+bias) + row L2-norm + BN partials; weight-stationary in VGPRs.
__global__ __launch_bounds__(512, 2) void k_linear(
    const u16* __restrict__ xb, u16* __restrict__ aggr /* in: aggr, out: hfrag */,
    const float* __restrict__ W, const float* __restrict__ b_lin,
    float* __restrict__ bnsum, float* __restrict__ bnsq,
    int n, int ntiles) {
    __shared__ u16 WT[32768];   // 64 KiB; repurposed after B-frag read
    int tid = threadIdx.x;

    // stage W (256x128 f32 [k][col]) -> WT bf16 [col][k], XOR-swizzle (col&15)<<3
    {
        int col = tid & 127;
        int kq0 = tid >> 7;            // 0..3
        int mask = (col & 15) << 3;
        char* base = (char*)WT + col * 512;
#pragma unroll
        for (int i = 0; i < 16; ++i) {
            int kq = kq0 + i * 4;      // quad index 0..63
            int k = kq * 4;
            float w0 = W[(size_t)(k + 0) * 128 + col];
            float w1 = W[(size_t)(k + 1) * 128 + col];
            float w2 = W[(size_t)(k + 2) * 128 + col];
            float w3 = W[(size_t)(k + 3) * 128 + col];
            u64 q = (u64)f2bf(w0) | ((u64)f2bf(w1) << 16) |
                    ((u64)f2bf(w2) << 32) | ((u64)f2bf(w3) << 48);
            *(u64*)(base + ((8 * kq) ^ mask)) = q;
        }
    }
    __syncthreads();

    int wave = tid >> 6, l = tid & 63, lr = l & 15, lg = l >> 4;
    int pair = wave >> 1, hf = wave & 1;

    // ---- read this wave's B-fragments into registers (one time) ----
    short8 breg[4][8];
#pragma unroll
    for (int ct2 = 0; ct2 < 4; ++ct2) {
        int col = hf * 64 + ct2 * 16 + lr;
        const char* rowp = (const char*)WT + col * 512;
        int mask = (col & 15) << 3;
#pragma unroll
        for (int kk = 0; kk < 8; ++kk) {
            int kb = kk * 64 + 8 * lg;
            u64 lo = *(const u64*)(rowp + (kb ^ mask));
            u64 hi = *(const u64*)(rowp + ((kb + 32) ^ mask));
            union { u64 q[2]; short8 v; } bu;
            bu.q[0] = lo; bu.q[1] = hi;
            breg[ct2][kk] = bu.v;
        }
    }
    __syncthreads();                 // all waves done with WT
    float* ssx = (float*)WT;         // [pair][hf][16] norm-exchange scratch

    float s1a[4] = {0, 0, 0, 0};
    float s2a[4] = {0, 0, 0, 0};
    int stride4 = gridDim.x * 4;

    for (int base = blockIdx.x * 4; base < ntiles; base += stride4) {
        int tile = base + pair;
        bool active = tile < ntiles;
        int rowA = tile * 16 + lr;
        bool rv = active && rowA < n;

        // ---- issue all A-operand loads (independent, both bf16) ----
        ushort4 xa[4], xc[4], ua[4], ub[4];
#pragma unroll
        for (int kk = 0; kk < 4; ++kk) {
            const u16* xp = xb + (size_t)rowA * 128 + kk * 32 + 4 * lg;
            xa[kk] = rv ? *(const ushort4*)xp : make_ushort4(0, 0, 0, 0);
            xc[kk] = rv ? *(const ushort4*)(xp + 16) : make_ushort4(0, 0, 0, 0);
        }
#pragma unroll
        for (int kk = 0; kk < 4; ++kk) {
            const u16* ap = aggr + (size_t)rowA * 128 + kk * 32 + 4 * lg;
            ua[kk] = rv ? *(const ushort4*)ap : make_ushort4(0, 0, 0, 0);
            ub[kk] = rv ? *(const ushort4*)(ap + 16) : make_ushort4(0, 0, 0, 0);
        }

        short8 av[8];
#pragma unroll
        for (int kk = 0; kk < 4; ++kk) {
            av[kk][0] = (short)xa[kk].x; av[kk][1] = (short)xa[kk].y;
            av[kk][2] = (short)xa[kk].z; av[kk][3] = (short)xa[kk].w;
            av[kk][4] = (short)xc[kk].x; av[kk][5] = (short)xc[kk].y;
            av[kk][6] = (short)xc[kk].z; av[kk][7] = (short)xc[kk].w;
            av[kk + 4][0] = (short)ua[kk].x; av[kk + 4][1] = (short)ua[kk].y;
            av[kk + 4][2] = (short)ua[kk].z; av[kk + 4][3] = (short)ua[kk].w;
            av[kk + 4][4] = (short)ub[kk].x; av[kk + 4][5] = (short)ub[kk].y;
            av[kk + 4][6] = (short)ub[kk].z; av[kk + 4][7] = (short)ub[kk].w;
        }

        f32x4 acc[4];
#pragma unroll
        for (int ct2 = 0; ct2 < 4; ++ct2) acc[ct2] = (f32x4){0.f, 0.f, 0.f, 0.f};
#pragma unroll
        for (int kk = 0; kk < 8; ++kk)
#pragma unroll
            for (int ct2 = 0; ct2 < 4; ++ct2)
                acc[ct2] = __builtin_amdgcn_mfma_f32_16x16x32_bf16(av[kk], breg[ct2][kk],
                                                                   acc[ct2], 0, 0, 0);

        // ---- epilogue: bias, half-row sumsq ----
        float ss[4] = {0.f, 0.f, 0.f, 0.f};
#pragma unroll
        for (int ct2 = 0; ct2 < 4; ++ct2) {
            float bl = b_lin[hf * 64 + ct2 * 16 + lr];
#pragma unroll
            for (int q = 0; q < 4; ++q) {
                acc[ct2][q] += bl;
                ss[q] += acc[ct2][q] * acc[ct2][q];
            }
        }
#pragma unroll
        for (int m = 1; m < 16; m <<= 1) {
#pragma unroll
            for (int q = 0; q < 4; ++q) ss[q] += __shfl_xor(ss[q], m, 64);
        }
        if (lr == 0)
            *(float4*)&ssx[(pair * 2 + hf) * 16 + lg * 4] =
                make_float4(ss[0], ss[1], ss[2], ss[3]);
        __syncthreads();
        float4 oth = *(const float4*)&ssx[(pair * 2 + (1 - hf)) * 16 + lg * 4];
        float sc[4];
        sc[0] = 1.0f / fmaxf(sqrtf(ss[0] + oth.x), 1e-12f);
        sc[1] = 1.0f / fmaxf(sqrtf(ss[1] + oth.y), 1e-12f);
        sc[2] = 1.0f / fmaxf(sqrtf(ss[2] + oth.z), 1e-12f);
        sc[3] = 1.0f / fmaxf(sqrtf(ss[3] + oth.w), 1e-12f);
        __syncthreads();   // WAR: protect ssx before next iteration

        if (active) {
            int rq0 = tile * 16 + 4 * lg;
#pragma unroll
            for (int ct2 = 0; ct2 < 4; ++ct2) {
                float hn[4];
                float p1 = 0.f, p2 = 0.f;
#pragma unroll
                for (int q = 0; q < 4; ++q) {
                    hn[q] = acc[ct2][q] * sc[q];
                    if (rq0 + q >= n) hn[q] = 0.f;
                    p1 += hn[q]; p2 += hn[q] * hn[q];
                }
                s1a[ct2] += p1; s2a[ct2] += p2;
                ushort4 o;
                o.x = f2bf(hn[0]); o.y = f2bf(hn[1]); o.z = f2bf(hn[2]); o.w = f2bf(hn[3]);
                *(ushort4*)(aggr + (size_t)tile * 2048 + (hf * 4 + ct2) * 256 + l * 4) = o;
            }
        }
    }

    // flush BN partials
#pragma unroll
    for (int ct2 = 0; ct2 < 4; ++ct2) {
        float v1 = s1a[ct2], v2 = s2a[ct2];
        v1 += __shfl_xor(v1, 16, 64); v1 += __shfl_xor(v1, 32, 64);
        v2 += __shfl_xor(v2, 16, 64); v2 += __shfl_xor(v2, 32, 64);
        if (lg == 0) {
            atomicAdd(&bnsum[hf * 64 + ct2 * 16 + lr], v1);
            atomicAdd(&bnsq[hf * 64 + ct2 * 16 + lr], v2);
        }
    }
}

// ------- pass2: BN apply from hfrag -> LDS tile -> coalesced residual+relu store
__global__ __launch_bounds__(512) void k_final(
    const u16* __restrict__ hfrag, const float* __restrict__ x,
    const float* __restrict__ bnsum, const float* __restrict__ bnsq,
    const float* __restrict__ gamma, const float* __restrict__ beta,
    float* __restrict__ out, float invN, int n) {
    __shared__ float cf[256];
    __shared__ float ot[16 * 132];
    int tid = threadIdx.x;
    int tile = blockIdx.x;
    if (tid < 128) {
        float mu = bnsum[tid] * invN;
        float var = bnsq[tid] * invN - mu * mu;
        float a = gamma[tid] * rsqrtf(var + 1e-5f);
        cf[tid] = a;
        cf[128 + tid] = beta[tid] - mu * a;
    }
    __syncthreads();

    {   // phase 1: BN apply into LDS tile
        int ct = tid >> 6, l = tid & 63;
        ushort4 hv = *(const ushort4*)(hfrag + (size_t)tile * 2048 + ct * 256 + l * 4);
        int col = ct * 16 + (l & 15);
        float a = cf[col], b = cf[128 + col];
        int rl0 = 4 * (l >> 4);
        ot[(rl0 + 0) * 132 + col] = bf2f(hv.x) * a + b;
        ot[(rl0 + 1) * 132 + col] = bf2f(hv.y) * a + b;
        ot[(rl0 + 2) * 132 + col] = bf2f(hv.z) * a + b;
        ot[(rl0 + 3) * 132 + col] = bf2f(hv.w) * a + b;
    }
    __syncthreads();

    {   // phase 2: + x residual, relu, coalesced float4 rows
        int rl = tid >> 5, c4 = tid & 31;
        int row = tile * 16 + rl;
        if (row < n) {
            float4 xv = *(const float4*)(x + (size_t)row * 128 + c4 * 4);
            const float* op = &ot[rl * 132 + c4 * 4];
            float4 o;
            o.x = fmaxf(op[0] + xv.x, 0.f);
            o.y = fmaxf(op[1] + xv.y, 0.f);
            o.z = fmaxf(op[2] + xv.z, 0.f);
            o.w = fmaxf(op[3] + xv.w, 0.f);
            *(float4*)(out + (size_t)row * 128 + c4 * 4) = o;
        }
    }
}

extern "C" void kernel_launch(void* const* d_in, const int* in_sizes, int n_in,
                              void* d_out, int out_size, void* d_ws, size_t ws_size,
                              hipStream_t stream) {
    const float* x     = (const float*)d_in[0];
    const int*   ei    = (const int*)d_in[1];
    const float* W     = (const float*)d_in[3];
    const float* b_lin = (const float*)d_in[4];
    const float* gamma = (const float*)d_in[5];
    const float* beta  = (const float*)d_in[6];
    int N = in_sizes[0] / 128;
    int E = in_sizes[1] / 2;
    const int* src = ei;
    const int* dst = ei + E;

    char* p = (char*)d_ws;
    auto alloc = [&](size_t bytes) { char* r = p; p += (bytes + 255) & ~(size_t)255; return r; };
    int*   deg   = (int*)alloc((size_t)N * 4);
    float* bnsum = (float*)alloc(128 * 4);
    float* bnsq  = (float*)alloc(128 * 4);
    int*   bcnt  = (int*)alloc(64 * 4);
    size_t zspan = (char*)(bcnt + 64) - (char*)deg;
    int*   off   = (int*)alloc((size_t)(N + 1) * 4);
    int*   cur   = (int*)alloc((size_t)N * 4);
    int*   csr   = (int*)alloc((size_t)E * 4);
    int*   bsum  = (int*)alloc(512 * 4);
    int*   boff  = (int*)alloc(512 * 4);
    u16*   aggr  = (u16*)alloc((size_t)N * 128 * 2);   // reused as hfrag by k_linear

    // d_out layout until k_final: [0,25.6MB) bf16 x-table; [25.6,51.2MB) buckets
    u16* xbf  = (u16*)d_out;
    int* bsrc = (int*)((char*)d_out + (size_t)N * 128 * 2);
    int  cap  = N * 4;                                  // per-bucket capacity (ints)
    int* bdst = bsrc + (size_t)8 * cap;

    hipMemsetAsync(deg, 0, zspan, stream);

    k_cvt<<<2048, 256, 0, stream>>>(x, xbf, N * 16);
    const int NGROUP = 8;
    int chunk = (N + NGROUP - 1) / NGROUP;
    k_bucket<<<512, 256, 0, stream>>>(src, dst, bcnt, bsrc, bdst, cap, E, chunk);
    k_deg2<<<1024, 256, 0, stream>>>(bdst, bcnt, deg, cap);
    int nb = (N + 255) / 256;
    k_scan_a<<<nb, 256, 0, stream>>>(deg, bsum, N);
    k_scan_b<<<1, 512, 0, stream>>>(bsum, boff, nb, off + N);
    k_scan_c<<<nb, 256, 0, stream>>>(deg, boff, off, cur, N);
    k_fill2<<<1024, 256, 0, stream>>>(bsrc, bdst, bcnt, cur, csr, cap);
    k_aggr<<<(int)(((size_t)N * 64 + 255) / 256), 256, 0, stream>>>(xbf, off, csr, aggr, N);
    int ntiles = (N + 15) / 16;
    k_linear<<<256, 512, 0, stream>>>(xbf, aggr, W, b_lin, bnsum, bnsq, N, ntiles);
    k_final<<<ntiles, 512, 0, stream>>>(aggr, x, bnsum, bnsq, gamma, beta,
                                        (float*)d_out, 1.0f / (float)N, N);
}

// Round 7
// 305.980 us; speedup vs baseline: 1.3435x; 1.3435x over previous
//
#include <hip/hip_runtime.h>
#include <hip/hip_bf16.h>

typedef __attribute__((ext_vector_type(4))) float f32x4;
typedef __attribute__((ext_vector_type(8))) short short8;
typedef unsigned short u16;
typedef unsigned long long u64;

static __device__ __forceinline__ u16 f2bf(float f) {
    __hip_bfloat16 h = __float2bfloat16(f);
    return __builtin_bit_cast(u16, h);
}
static __device__ __forceinline__ float bf2f(u16 u) {
    unsigned int w = ((unsigned int)u) << 16;
    return __builtin_bit_cast(float, w);
}

// ---------------- x (f32) -> x_bf (bf16) streaming convert ----------------
__global__ void k_cvt(const float* __restrict__ x, u16* __restrict__ xb, int total8) {
    const float4* x4 = (const float4*)x;
    int stride = gridDim.x * blockDim.x;
    for (int i = blockIdx.x * blockDim.x + threadIdx.x; i < total8; i += stride) {
        float4 a = x4[i * 2], b = x4[i * 2 + 1];
        union { u16 u[8]; short8 v; } o;
        o.u[0] = f2bf(a.x); o.u[1] = f2bf(a.y); o.u[2] = f2bf(a.z); o.u[3] = f2bf(a.w);
        o.u[4] = f2bf(b.x); o.u[5] = f2bf(b.y); o.u[6] = f2bf(b.z); o.u[7] = f2bf(b.w);
        *(short8*)(xb + (size_t)i * 8) = o.v;
    }
}

// ---------------- degree count: dst-range groups PINNED to XCDs ----------------
// group = blockIdx.x & 7 -> all blocks of group g land on XCD g (round-robin
// dispatch). Group g only counts dst in its range, so its 50KB deg slice stays
// in ONE L2 -> no cross-XCD atomic ping-pong.
__global__ void k_deg(const int* __restrict__ dst, int* __restrict__ deg,
                      int E, int chunk) {
    const int NX = 8;
    int group = blockIdx.x & (NX - 1);
    int bseq = blockIdx.x >> 3;
    int nblk = gridDim.x >> 3;
    int lo = group * chunk, hi = lo + chunk;
    int E4 = E >> 2;
    const int4* d4 = (const int4*)dst;
    int stride = nblk * blockDim.x;
    int gid = bseq * blockDim.x + threadIdx.x;
    for (int i = gid; i < E4; i += stride) {
        int4 v = d4[i];
        if (v.x >= lo && v.x < hi) atomicAdd(&deg[v.x], 1);
        if (v.y >= lo && v.y < hi) atomicAdd(&deg[v.y], 1);
        if (v.z >= lo && v.z < hi) atomicAdd(&deg[v.z], 1);
        if (v.w >= lo && v.w < hi) atomicAdd(&deg[v.w], 1);
    }
    if (group == 0) {
        for (int e = E4 * 4 + gid; e < E; e += stride)
            atomicAdd(&deg[dst[e]], 1);
    }
}

// ---------------- 3-kernel exclusive scan over deg[N] ----------------
__global__ void k_scan_a(const int* __restrict__ deg, int* __restrict__ bsum, int n) {
    __shared__ int s[256];
    int tid = threadIdx.x;
    int i = blockIdx.x * 256 + tid;
    s[tid] = (i < n) ? deg[i] : 0;
    __syncthreads();
    for (int ofs = 128; ofs > 0; ofs >>= 1) {
        if (tid < ofs) s[tid] += s[tid + ofs];
        __syncthreads();
    }
    if (tid == 0) bsum[blockIdx.x] = s[0];
}

__global__ void k_scan_b(const int* __restrict__ bsum, int* __restrict__ boff, int nb,
                         int* __restrict__ offN) {
    __shared__ int s[512];
    int tid = threadIdx.x;
    int v = (tid < nb) ? bsum[tid] : 0;
    s[tid] = v;
    __syncthreads();
    for (int ofs = 1; ofs < 512; ofs <<= 1) {
        int t = (tid >= ofs) ? s[tid - ofs] : 0;
        __syncthreads();
        s[tid] += t;
        __syncthreads();
    }
    if (tid < nb) boff[tid] = s[tid] - v;          // exclusive
    if (tid == nb - 1) offN[0] = s[tid];           // total = E
}

__global__ void k_scan_c(const int* __restrict__ deg, const int* __restrict__ boff,
                         int* __restrict__ off, int* __restrict__ cur, int n) {
    __shared__ int s[256];
    int tid = threadIdx.x;
    int i = blockIdx.x * 256 + tid;
    int v = (i < n) ? deg[i] : 0;
    s[tid] = v;
    __syncthreads();
    for (int ofs = 1; ofs < 256; ofs <<= 1) {
        int t = (tid >= ofs) ? s[tid - ofs] : 0;
        __syncthreads();
        s[tid] += t;
        __syncthreads();
    }
    int excl = s[tid] - v + boff[blockIdx.x];
    if (i < n) { off[i] = excl; cur[i] = excl; }
}

// ---------------- CSR fill: dst-range groups PINNED to XCDs -------------------
__global__ void k_fill(const int* __restrict__ src, const int* __restrict__ dst,
                       int* __restrict__ cur, int* __restrict__ csr, int E, int chunk) {
    const int NX = 8;
    int group = blockIdx.x & (NX - 1);
    int bseq = blockIdx.x >> 3;
    int nblk = gridDim.x >> 3;
    int lo = group * chunk, hi = lo + chunk;
    int E4 = E >> 2;
    const int4* d4 = (const int4*)dst;
    int stride = nblk * blockDim.x;
    int gid = bseq * blockDim.x + threadIdx.x;
    for (int i = gid; i < E4; i += stride) {
        int4 v = d4[i];
        int e = i * 4;
        if (v.x >= lo && v.x < hi) { int p = atomicAdd(&cur[v.x], 1); csr[p] = src[e]; }
        if (v.y >= lo && v.y < hi) { int p = atomicAdd(&cur[v.y], 1); csr[p] = src[e + 1]; }
        if (v.z >= lo && v.z < hi) { int p = atomicAdd(&cur[v.z], 1); csr[p] = src[e + 2]; }
        if (v.w >= lo && v.w < hi) { int p = atomicAdd(&cur[v.w], 1); csr[p] = src[e + 3]; }
    }
    if (group == 0) {
        for (int e = E4 * 4 + gid; e < E; e += stride) {
            int d = dst[e];
            int p = atomicAdd(&cur[d], 1);
            csr[p] = src[e];
        }
    }
}

// ------ pull-aggregate: one wave per node, 4 edge slots x 16 lanes x 16B --------
__global__ void k_aggr(const u16* __restrict__ xb, const int* __restrict__ off,
                       const int* __restrict__ csr, u16* __restrict__ aggr, int n) {
    int node = (blockIdx.x * blockDim.x + threadIdx.x) >> 6;
    if (node >= n) return;
    int lane = threadIdx.x & 63;
    int c = lane & 15;    // 16B slot (8 bf16), 16 slots = 256B row
    int j = lane >> 4;    // edge slot 0..3
    const short8* x8 = (const short8*)xb;
    int s0 = off[node], s1 = off[node + 1];
    float acc[8] = {0.f, 0.f, 0.f, 0.f, 0.f, 0.f, 0.f, 0.f};
    int e = s0;
    for (; e + 8 <= s1; e += 8) {   // 2 rows per slot in flight (8 rows/wave)
        short8 va = x8[(size_t)csr[e + j] * 16 + c];
        short8 vb = x8[(size_t)csr[e + j + 4] * 16 + c];
#pragma unroll
        for (int i = 0; i < 8; ++i)
            acc[i] += bf2f((u16)va[i]) + bf2f((u16)vb[i]);
    }
    {   // tail: up to 7 edges, per-slot guards
        int r1 = e + j, r2 = e + j + 4;
        if (r1 < s1) {
            short8 va = x8[(size_t)csr[r1] * 16 + c];
#pragma unroll
            for (int i = 0; i < 8; ++i) acc[i] += bf2f((u16)va[i]);
        }
        if (r2 < s1) {
            short8 vb = x8[(size_t)csr[r2] * 16 + c];
#pragma unroll
            for (int i = 0; i < 8; ++i) acc[i] += bf2f((u16)vb[i]);
        }
    }
#pragma unroll
    for (int i = 0; i < 8; ++i) {
        acc[i] += __shfl_xor(acc[i], 16, 64);
        acc[i] += __shfl_xor(acc[i], 32, 64);
    }
    if (j == 0) {
        short8 sv = x8[(size_t)node * 16 + c];   // self loop
        float inv = 1.0f / (float)(s1 - s0 + 1);
        short8 o;
#pragma unroll
        for (int i = 0; i < 8; ++i)
            o[i] = (short)f2bf((acc[i] + bf2f((u16)sv[i])) * inv);
        *(short8*)(aggr + (size_t)node * 128 + c * 8) = o;
    }
}

// ------- pass1: linear(+bias) + row L2-norm + BN partials; weight-stationary in VGPRs.
__global__ __launch_bounds__(512, 2) void k_linear(
    const u16* __restrict__ xb, u16* __restrict__ aggr /* in: aggr, out: hfrag */,
    const float* __restrict__ W, const float* __restrict__ b_lin,
    float* __restrict__ bnsum, float* __restrict__ bnsq,
    int n, int ntiles) {
    __shared__ u16 WT[32768];   // 64 KiB; repurposed after B-frag read
    int tid = threadIdx.x;

    // stage W (256x128 f32 [k][col]) -> WT bf16 [col][k], XOR-swizzle (col&15)<<3
    {
        int col = tid & 127;
        int kq0 = tid >> 7;            // 0..3
        int mask = (col & 15) << 3;
        char* base = (char*)WT + col * 512;
#pragma unroll
        for (int i = 0; i < 16; ++i) {
            int kq = kq0 + i * 4;      // quad index 0..63
            int k = kq * 4;
            float w0 = W[(size_t)(k + 0) * 128 + col];
            float w1 = W[(size_t)(k + 1) * 128 + col];
            float w2 = W[(size_t)(k + 2) * 128 + col];
            float w3 = W[(size_t)(k + 3) * 128 + col];
            u64 q = (u64)f2bf(w0) | ((u64)f2bf(w1) << 16) |
                    ((u64)f2bf(w2) << 32) | ((u64)f2bf(w3) << 48);
            *(u64*)(base + ((8 * kq) ^ mask)) = q;
        }
    }
    __syncthreads();

    int wave = tid >> 6, l = tid & 63, lr = l & 15, lg = l >> 4;
    int pair = wave >> 1, hf = wave & 1;

    // ---- read this wave's B-fragments into registers (one time) ----
    short8 breg[4][8];
#pragma unroll
    for (int ct2 = 0; ct2 < 4; ++ct2) {
        int col = hf * 64 + ct2 * 16 + lr;
        const char* rowp = (const char*)WT + col * 512;
        int mask = (col & 15) << 3;
#pragma unroll
        for (int kk = 0; kk < 8; ++kk) {
            int kb = kk * 64 + 8 * lg;
            u64 lo = *(const u64*)(rowp + (kb ^ mask));
            u64 hi = *(const u64*)(rowp + ((kb + 32) ^ mask));
            union { u64 q[2]; short8 v; } bu;
            bu.q[0] = lo; bu.q[1] = hi;
            breg[ct2][kk] = bu.v;
        }
    }
    __syncthreads();                 // all waves done with WT
    float* ssx = (float*)WT;         // [pair][hf][16] norm-exchange scratch

    float s1a[4] = {0, 0, 0, 0};
    float s2a[4] = {0, 0, 0, 0};
    int stride4 = gridDim.x * 4;

    for (int base = blockIdx.x * 4; base < ntiles; base += stride4) {
        int tile = base + pair;
        bool active = tile < ntiles;
        int rowA = tile * 16 + lr;
        bool rv = active && rowA < n;

        // ---- issue all A-operand loads (independent, both bf16) ----
        ushort4 xa[4], xc[4], ua[4], ub[4];
#pragma unroll
        for (int kk = 0; kk < 4; ++kk) {
            const u16* xp = xb + (size_t)rowA * 128 + kk * 32 + 4 * lg;
            xa[kk] = rv ? *(const ushort4*)xp : make_ushort4(0, 0, 0, 0);
            xc[kk] = rv ? *(const ushort4*)(xp + 16) : make_ushort4(0, 0, 0, 0);
        }
#pragma unroll
        for (int kk = 0; kk < 4; ++kk) {
            const u16* ap = aggr + (size_t)rowA * 128 + kk * 32 + 4 * lg;
            ua[kk] = rv ? *(const ushort4*)ap : make_ushort4(0, 0, 0, 0);
            ub[kk] = rv ? *(const ushort4*)(ap + 16) : make_ushort4(0, 0, 0, 0);
        }

        short8 av[8];
#pragma unroll
        for (int kk = 0; kk < 4; ++kk) {
            av[kk][0] = (short)xa[kk].x; av[kk][1] = (short)xa[kk].y;
            av[kk][2] = (short)xa[kk].z; av[kk][3] = (short)xa[kk].w;
            av[kk][4] = (short)xc[kk].x; av[kk][5] = (short)xc[kk].y;
            av[kk][6] = (short)xc[kk].z; av[kk][7] = (short)xc[kk].w;
            av[kk + 4][0] = (short)ua[kk].x; av[kk + 4][1] = (short)ua[kk].y;
            av[kk + 4][2] = (short)ua[kk].z; av[kk + 4][3] = (short)ua[kk].w;
            av[kk + 4][4] = (short)ub[kk].x; av[kk + 4][5] = (short)ub[kk].y;
            av[kk + 4][6] = (short)ub[kk].z; av[kk + 4][7] = (short)ub[kk].w;
        }

        f32x4 acc[4];
#pragma unroll
        for (int ct2 = 0; ct2 < 4; ++ct2) acc[ct2] = (f32x4){0.f, 0.f, 0.f, 0.f};
#pragma unroll
        for (int kk = 0; kk < 8; ++kk)
#pragma unroll
            for (int ct2 = 0; ct2 < 4; ++ct2)
                acc[ct2] = __builtin_amdgcn_mfma_f32_16x16x32_bf16(av[kk], breg[ct2][kk],
                                                                   acc[ct2], 0, 0, 0);

        // ---- epilogue: bias, half-row sumsq ----
        float ss[4] = {0.f, 0.f, 0.f, 0.f};
#pragma unroll
        for (int ct2 = 0; ct2 < 4; ++ct2) {
            float bl = b_lin[hf * 64 + ct2 * 16 + lr];
#pragma unroll
            for (int q = 0; q < 4; ++q) {
                acc[ct2][q] += bl;
                ss[q] += acc[ct2][q] * acc[ct2][q];
            }
        }
#pragma unroll
        for (int m = 1; m < 16; m <<= 1) {
#pragma unroll
            for (int q = 0; q < 4; ++q) ss[q] += __shfl_xor(ss[q], m, 64);
        }
        if (lr == 0)
            *(float4*)&ssx[(pair * 2 + hf) * 16 + lg * 4] =
                make_float4(ss[0], ss[1], ss[2], ss[3]);
        __syncthreads();
        float4 oth = *(const float4*)&ssx[(pair * 2 + (1 - hf)) * 16 + lg * 4];
        float sc[4];
        sc[0] = 1.0f / fmaxf(sqrtf(ss[0] + oth.x), 1e-12f);
        sc[1] = 1.0f / fmaxf(sqrtf(ss[1] + oth.y), 1e-12f);
        sc[2] = 1.0f / fmaxf(sqrtf(ss[2] + oth.z), 1e-12f);
        sc[3] = 1.0f / fmaxf(sqrtf(ss[3] + oth.w), 1e-12f);
        __syncthreads();   // WAR: protect ssx before next iteration

        if (active) {
            int rq0 = tile * 16 + 4 * lg;
#pragma unroll
            for (int ct2 = 0; ct2 < 4; ++ct2) {
                float hn[4];
                float p1 = 0.f, p2 = 0.f;
#pragma unroll
                for (int q = 0; q < 4; ++q) {
                    hn[q] = acc[ct2][q] * sc[q];
                    if (rq0 + q >= n) hn[q] = 0.f;
                    p1 += hn[q]; p2 += hn[q] * hn[q];
                }
                s1a[ct2] += p1; s2a[ct2] += p2;
                ushort4 o;
                o.x = f2bf(hn[0]); o.y = f2bf(hn[1]); o.z = f2bf(hn[2]); o.w = f2bf(hn[3]);
                *(ushort4*)(aggr + (size_t)tile * 2048 + (hf * 4 + ct2) * 256 + l * 4) = o;
            }
        }
    }

    // flush BN partials
#pragma unroll
    for (int ct2 = 0; ct2 < 4; ++ct2) {
        float v1 = s1a[ct2], v2 = s2a[ct2];
        v1 += __shfl_xor(v1, 16, 64); v1 += __shfl_xor(v1, 32, 64);
        v2 += __shfl_xor(v2, 16, 64); v2 += __shfl_xor(v2, 32, 64);
        if (lg == 0) {
            atomicAdd(&bnsum[hf * 64 + ct2 * 16 + lr], v1);
            atomicAdd(&bnsq[hf * 64 + ct2 * 16 + lr], v2);
        }
    }
}

// ------- pass2: BN apply from hfrag -> LDS tile -> coalesced residual+relu store
__global__ __launch_bounds__(512) void k_final(
    const u16* __restrict__ hfrag, const float* __restrict__ x,
    const float* __restrict__ bnsum, const float* __restrict__ bnsq,
    const float* __restrict__ gamma, const float* __restrict__ beta,
    float* __restrict__ out, float invN, int n) {
    __shared__ float cf[256];
    __shared__ float ot[16 * 132];
    int tid = threadIdx.x;
    int tile = blockIdx.x;
    if (tid < 128) {
        float mu = bnsum[tid] * invN;
        float var = bnsq[tid] * invN - mu * mu;
        float a = gamma[tid] * rsqrtf(var + 1e-5f);
        cf[tid] = a;
        cf[128 + tid] = beta[tid] - mu * a;
    }
    __syncthreads();

    {   // phase 1: BN apply into LDS tile
        int ct = tid >> 6, l = tid & 63;
        ushort4 hv = *(const ushort4*)(hfrag + (size_t)tile * 2048 + ct * 256 + l * 4);
        int col = ct * 16 + (l & 15);
        float a = cf[col], b = cf[128 + col];
        int rl0 = 4 * (l >> 4);
        ot[(rl0 + 0) * 132 + col] = bf2f(hv.x) * a + b;
        ot[(rl0 + 1) * 132 + col] = bf2f(hv.y) * a + b;
        ot[(rl0 + 2) * 132 + col] = bf2f(hv.z) * a + b;
        ot[(rl0 + 3) * 132 + col] = bf2f(hv.w) * a + b;
    }
    __syncthreads();

    {   // phase 2: + x residual, relu, coalesced float4 rows
        int rl = tid >> 5, c4 = tid & 31;
        int row = tile * 16 + rl;
        if (row < n) {
            float4 xv = *(const float4*)(x + (size_t)row * 128 + c4 * 4);
            const float* op = &ot[rl * 132 + c4 * 4];
            float4 o;
            o.x = fmaxf(op[0] + xv.x, 0.f);
            o.y = fmaxf(op[1] + xv.y, 0.f);
            o.z = fmaxf(op[2] + xv.z, 0.f);
            o.w = fmaxf(op[3] + xv.w, 0.f);
            *(float4*)(out + (size_t)row * 128 + c4 * 4) = o;
        }
    }
}

extern "C" void kernel_launch(void* const* d_in, const int* in_sizes, int n_in,
                              void* d_out, int out_size, void* d_ws, size_t ws_size,
                              hipStream_t stream) {
    const float* x     = (const float*)d_in[0];
    const int*   ei    = (const int*)d_in[1];
    const float* W     = (const float*)d_in[3];
    const float* b_lin = (const float*)d_in[4];
    const float* gamma = (const float*)d_in[5];
    const float* beta  = (const float*)d_in[6];
    int N = in_sizes[0] / 128;
    int E = in_sizes[1] / 2;
    const int* src = ei;
    const int* dst = ei + E;

    char* p = (char*)d_ws;
    auto alloc = [&](size_t bytes) { char* r = p; p += (bytes + 255) & ~(size_t)255; return r; };
    int*   deg   = (int*)alloc((size_t)N * 4);
    float* bnsum = (float*)alloc(128 * 4);
    float* bnsq  = (float*)alloc(128 * 4);
    size_t zspan = (char*)(bnsq + 128) - (char*)deg;
    int*   off   = (int*)alloc((size_t)(N + 1) * 4);
    int*   cur   = (int*)alloc((size_t)N * 4);
    int*   csr   = (int*)alloc((size_t)E * 4);
    int*   bsum  = (int*)alloc(512 * 4);
    int*   boff  = (int*)alloc(512 * 4);
    u16*   aggr  = (u16*)alloc((size_t)N * 128 * 2);   // reused as hfrag by k_linear

    // bf16 x-table lives in d_out (dead until k_final overwrites all of it)
    u16* xbf = (u16*)d_out;

    hipMemsetAsync(deg, 0, zspan, stream);

    const int NGROUP = 8;
    int chunk = (N + NGROUP - 1) / NGROUP;

    k_cvt<<<2048, 256, 0, stream>>>(x, xbf, N * 16);
    k_deg<<<1024, 256, 0, stream>>>(dst, deg, E, chunk);
    int nb = (N + 255) / 256;
    k_scan_a<<<nb, 256, 0, stream>>>(deg, bsum, N);
    k_scan_b<<<1, 512, 0, stream>>>(bsum, boff, nb, off + N);
    k_scan_c<<<nb, 256, 0, stream>>>(deg, boff, off, cur, N);
    k_fill<<<1024, 256, 0, stream>>>(src, dst, cur, csr, E, chunk);
    k_aggr<<<(int)(((size_t)N * 64 + 255) / 256), 256, 0, stream>>>(xbf, off, csr, aggr, N);
    int ntiles = (N + 15) / 16;
    k_linear<<<256, 512, 0, stream>>>(xbf, aggr, W, b_lin, bnsum, bnsq, N, ntiles);
    k_final<<<ntiles, 512, 0, stream>>>(aggr, x, bnsum, bnsq, gamma, beta,
                                        (float*)d_out, 1.0f / (float)N, N);
}